// Round 1
// baseline (2544.956 us; speedup 1.0000x reference)
//
#include <hip/hip_runtime.h>
#include <math.h>

// ---------------------------------------------------------------------------
// MCGDecoder: 5 iterations of dual-MLP (s: 49152x256 rows, c: 8192x256 rows)
// with residual mixing + max-over-T aggregation, then a 256->512->401 decoder
// and an exp/sinh/cosh covariance epilogue.
//
// Round 0: correct fp32 baseline.
//  - iter-0 s-MLP computed on only the 6 anchor rows (s is (b,a)-invariant
//    before the first c_new multiply) -> saves ~13% FLOPs.
//  - s/c initialization folded into the iter-0 elementwise kernel.
//  - GEMM: 64x64 tile, 256 threads, 4x4 acc/thread, BK=16, LDS-staged,
//    fused bias (+optional ReLU) epilogue, M/N guarded (handles M=6, N=401).
// ---------------------------------------------------------------------------

constexpr int Tn  = 6;
constexpr int Dn  = 256;
constexpr int Hn  = 512;
constexpr int NBn = 5;
constexpr int OUTn = 401;
constexpr int BA  = 64 * 128;   // 8192 (b*a)
constexpr int MR  = BA * Tn;    // 49152 rows of s
constexpr float kAlpha = 0.5f;
constexpr float kBeta  = 0.5f;

// ---- GEMM: C = act(X @ W + bias); X:(M,K) row-major, W:(K,N) row-major ----
template<bool RELU>
__global__ __launch_bounds__(256) void gemm_bias_act(
    const float* __restrict__ X, const float* __restrict__ W,
    const float* __restrict__ bias, float* __restrict__ C,
    int M, int N, int K)
{
  __shared__ float As[16][64];   // [k][m]
  __shared__ float Bs[16][64];   // [k][n]
  const int tid = threadIdx.x;
  const int tx = tid & 15;       // n-group
  const int ty = tid >> 4;       // m-group
  const int m0 = blockIdx.y * 64;
  const int n0 = blockIdx.x * 64;

  float acc[4][4] = {};

  for (int k0 = 0; k0 < K; k0 += 16) {
#pragma unroll
    for (int i = 0; i < 4; ++i) {
      int e  = tid + i * 256;
      int ar = e >> 4, ak = e & 15;       // A: 64 rows x 16 k
      int gm = m0 + ar;
      As[ak][ar] = (gm < M) ? X[(long)gm * K + (k0 + ak)] : 0.0f;
      int bk = e >> 6, bn = e & 63;       // B: 16 k x 64 n
      int gn = n0 + bn;
      Bs[bk][bn] = (gn < N) ? W[(long)(k0 + bk) * N + gn] : 0.0f;
    }
    __syncthreads();
#pragma unroll
    for (int kk = 0; kk < 16; ++kk) {
      float a[4], b[4];
#pragma unroll
      for (int i = 0; i < 4; ++i) a[i] = As[kk][ty * 4 + i];
#pragma unroll
      for (int j = 0; j < 4; ++j) b[j] = Bs[kk][tx * 4 + j];
#pragma unroll
      for (int i = 0; i < 4; ++i)
#pragma unroll
        for (int j = 0; j < 4; ++j)
          acc[i][j] = fmaf(a[i], b[j], acc[i][j]);
    }
    __syncthreads();
  }

#pragma unroll
  for (int i = 0; i < 4; ++i) {
    int gm = m0 + ty * 4 + i;
    if (gm >= M) continue;
#pragma unroll
    for (int j = 0; j < 4; ++j) {
      int gn = n0 + tx * 4 + j;
      if (gn >= N) continue;
      float v = acc[i][j] + bias[gn];
      if (RELU) v = fmaxf(v, 0.0f);
      C[(long)gm * N + gn] = v;
    }
  }
}

// ---- iter-0 elementwise: folds s/c init + first update ----
// s[ba,t,d] = 0.5*anchor[t,d] + 0.5*(snew_small[t,d]*cnew[ba,d])
// c[ba,d]   = 0.5*fe[ba,d]    + 0.5*max_t(snew_small[t,d]*cnew[ba,d])
__global__ __launch_bounds__(256) void ew_update0(
    const float* __restrict__ anchor, const float* __restrict__ fe,
    const float* __restrict__ snew_small, const float* __restrict__ cnew,
    float* __restrict__ s, float* __restrict__ c)
{
  int q = blockIdx.x * blockDim.x + threadIdx.x;   // over BA*Dn
  if (q >= BA * Dn) return;
  int ba = q >> 8;
  int n  = q & 255;
  float cn = cnew[q];
  float m = -3.402823466e38f;
  long base = (long)ba * Tn * Dn + n;
#pragma unroll
  for (int t = 0; t < Tn; ++t) {
    float sn = snew_small[t * Dn + n] * cn;
    m = fmaxf(m, sn);
    s[base + t * Dn] = kAlpha * anchor[t * Dn + n] + kBeta * sn;
  }
  c[q] = kAlpha * fe[q] + kBeta * m;
}

// ---- per-iteration elementwise update ----
__global__ __launch_bounds__(256) void ew_update(
    const float* __restrict__ snew, const float* __restrict__ cnew,
    float* __restrict__ s, float* __restrict__ c)
{
  int q = blockIdx.x * blockDim.x + threadIdx.x;   // over BA*Dn
  if (q >= BA * Dn) return;
  int ba = q >> 8;
  int n  = q & 255;
  float cn = cnew[q];
  float m = -3.402823466e38f;
  long base = (long)ba * Tn * Dn + n;
#pragma unroll
  for (int t = 0; t < Tn; ++t) {
    long idx = base + t * Dn;
    float sn = snew[idx] * cn;
    m = fmaxf(m, sn);
    s[idx] = kAlpha * s[idx] + kBeta * sn;
  }
  c[q] = kAlpha * c[q] + kBeta * m;
}

// ---- final epilogue: res(49152,401) -> probas | coords | covariance ----
__global__ __launch_bounds__(256) void final_epilogue(
    const float* __restrict__ res, float* __restrict__ out)
{
  int q = blockIdx.x * blockDim.x + threadIdx.x;   // over MR*80
  if (q >= MR * 80) return;
  int r = q / 80;
  int j = q - r * 80;
  const float* row = res + (long)r * OUTn;

  float x  = row[2 * j];
  float y  = row[2 * j + 1];
  float av = row[160 + j];
  float bv = row[240 + j];
  float cv = row[320 + j];

  float ea = expf(av);
  float ec = expf(cv);
  float sh = sinhf(bv);
  float ch = coshf(bv);

  float* coords = out + MR;                    // after probas (MR floats)
  float* cov    = coords + (long)MR * 160;     // after coords
  long cbase = (long)r * 160 + 2 * j;
  coords[cbase]     = x;
  coords[cbase + 1] = y;
  long vb = (long)r * 320 + j * 4;
  cov[vb + 0] = ea * ch * ec;
  cov[vb + 1] = sh * ec;
  cov[vb + 2] = sh * ec;
  cov[vb + 3] = ch / ea * ec;                  // exp(-av)*cosh(bv)*exp(cv)

  if (j == 0) out[r] = row[400];               // probas
}

// ---------------------------------------------------------------------------
extern "C" void kernel_launch(void* const* d_in, const int* in_sizes, int n_in,
                              void* d_out, int out_size, void* d_ws, size_t ws_size,
                              hipStream_t stream) {
  const float* fe     = (const float*)d_in[0];   // (8192, 256)
  const float* anchor = (const float*)d_in[1];   // (6, 256)
  const float* sW1 = (const float*)d_in[2];
  const float* sb1 = (const float*)d_in[3];
  const float* sW2 = (const float*)d_in[4];
  const float* sb2 = (const float*)d_in[5];
  const float* cW1 = (const float*)d_in[6];
  const float* cb1 = (const float*)d_in[7];
  const float* cW2 = (const float*)d_in[8];
  const float* cb2 = (const float*)d_in[9];
  const float* dW1 = (const float*)d_in[10];
  const float* db1 = (const float*)d_in[11];
  const float* dW2 = (const float*)d_in[12];
  const float* db2 = (const float*)d_in[13];
  float* out = (float*)d_out;

  // workspace layout (floats)
  float* s    = (float*)d_ws;                 // 12,582,912
  float* snew = s    + (size_t)MR * Dn;       // 12,582,912
  float* hd   = snew + (size_t)MR * Dn;       // 25,165,824 (hs = first half)
  float* hs   = hd;
  float* c    = hd   + (size_t)MR * Hn;       // 2,097,152
  float* hc   = c    + (size_t)BA * Dn;       // 2,097,152
  float* cnew = hc   + (size_t)BA * Dn;       // 2,097,152
  float* hs_small   = cnew + (size_t)BA * Dn; // 1536
  float* snew_small = hs_small + Tn * Dn;     // 1536
  float* res  = s;   // alias over s+snew (dead by then): needs 19.7M <= 25.1M

  auto gemm = [&](const float* X, const float* W, const float* b, float* C,
                  int M, int N, int K, bool relu) {
    dim3 grid((N + 63) / 64, (M + 63) / 64);
    if (relu)
      gemm_bias_act<true ><<<grid, 256, 0, stream>>>(X, W, b, C, M, N, K);
    else
      gemm_bias_act<false><<<grid, 256, 0, stream>>>(X, W, b, C, M, N, K);
  };

  const int ewBlocks = (BA * Dn + 255) / 256;

  // -------- iteration 0 (s is (b,a)-invariant: MLP on 6 anchor rows only) --
  gemm(anchor,   sW1, sb1, hs_small,   Tn, Dn, Dn, true);
  gemm(hs_small, sW2, sb2, snew_small, Tn, Dn, Dn, false);
  gemm(fe, cW1, cb1, hc,   BA, Dn, Dn, true);
  gemm(hc, cW2, cb2, cnew, BA, Dn, Dn, false);
  ew_update0<<<ewBlocks, 256, 0, stream>>>(anchor, fe, snew_small, cnew, s, c);

  // -------- iterations 1..4 --------
  for (int i = 1; i < NBn; ++i) {
    const float* sw1 = sW1 + (size_t)i * Dn * Dn;
    const float* sw2 = sW2 + (size_t)i * Dn * Dn;
    const float* cw1 = cW1 + (size_t)i * Dn * Dn;
    const float* cw2 = cW2 + (size_t)i * Dn * Dn;
    gemm(s,  sw1, sb1 + i * Dn, hs,   MR, Dn, Dn, true);
    gemm(hs, sw2, sb2 + i * Dn, snew, MR, Dn, Dn, false);
    gemm(c,  cw1, cb1 + i * Dn, hc,   BA, Dn, Dn, true);
    gemm(hc, cw2, cb2 + i * Dn, cnew, BA, Dn, Dn, false);
    ew_update<<<ewBlocks, 256, 0, stream>>>(snew, cnew, s, c);
  }

  // -------- decoder --------
  gemm(s,  dW1, db1, hd,  MR, Hn,   Dn, true);
  gemm(hd, dW2, db2, res, MR, OUTn, Hn, false);

  final_epilogue<<<(MR * 80 + 255) / 256, 256, 0, stream>>>(res, out);
}

// Round 2
// 807.192 us; speedup vs baseline: 3.1529x; 3.1529x over previous
//
#include <hip/hip_runtime.h>
#include <math.h>

// ---------------------------------------------------------------------------
// Round 2: bf16-MFMA GEMM chain (m97 structure: 128x128 tile, BK=32,
// global_load_lds width-16, pre-transposed bf16 weights), fp32 master states
// and elementwise math. Outputs feeding elementwise kept fp32; GEMM->GEMM
// intermediates stored bf16.
// ---------------------------------------------------------------------------

constexpr int Tn  = 6;
constexpr int Dn  = 256;
constexpr int Hn  = 512;
constexpr int NBn = 5;
constexpr int OUTn = 401;
constexpr int BA  = 64 * 128;   // 8192
constexpr int MR  = BA * Tn;    // 49152
constexpr float kAlpha = 0.5f;
constexpr float kBeta  = 0.5f;

typedef __bf16 bf16_8 __attribute__((ext_vector_type(8)));
typedef float  f32x4  __attribute__((ext_vector_type(4)));

__device__ __forceinline__ void async_copy16(const __bf16* g, __bf16* l) {
  __builtin_amdgcn_global_load_lds(
      (const __attribute__((address_space(1))) void*)g,
      (__attribute__((address_space(3))) void*)l, 16, 0, 0);
}

// ---- GEMM: C = act(A @ BT^T + bias) ----------------------------------------
// A: (M,K) bf16 row-major, stride K.  BT: (N,K) bf16 row-major (W^T).
// C: (M,N), fp32 or bf16. M,N arbitrary (addresses clamped; stores guarded),
// K multiple of 32.
template<bool RELU, bool OUT_BF16>
__global__ __launch_bounds__(256) void gemm_mfma(
    const __bf16* __restrict__ A, const __bf16* __restrict__ BT,
    const float* __restrict__ bias, void* __restrict__ Cout,
    int M, int N, int K)
{
  __shared__ __bf16 As[128 * 32];
  __shared__ __bf16 Bs[128 * 32];
  const int tid = threadIdx.x;
  const int l   = tid & 63;
  const int w   = tid >> 6;          // wave 0..3
  const int wm  = w >> 1, wn = w & 1;
  const int m0  = blockIdx.y * 128;
  const int n0  = blockIdx.x * 128;

  // staging: 8 chunks of 16 rows per tile; wave w handles chunks 2w,2w+1
  const int lrow = l >> 2;           // 0..15 (row within chunk)
  const int lk   = (l & 3) * 8;      // k element offset (8 bf16 = 16B)
  int ar0 = m0 + w * 32 + lrow;        if (ar0 > M - 1) ar0 = M - 1;
  int ar1 = m0 + w * 32 + 16 + lrow;   if (ar1 > M - 1) ar1 = M - 1;
  int br0 = n0 + w * 32 + lrow;        if (br0 > N - 1) br0 = N - 1;
  int br1 = n0 + w * 32 + 16 + lrow;   if (br1 > N - 1) br1 = N - 1;
  const __bf16* Ag0 = A  + (size_t)ar0 * K + lk;
  const __bf16* Ag1 = A  + (size_t)ar1 * K + lk;
  const __bf16* Bg0 = BT + (size_t)br0 * K + lk;
  const __bf16* Bg1 = BT + (size_t)br1 * K + lk;
  __bf16* Al = As + w * 1024;        // elements (chunk pair base)
  __bf16* Bl = Bs + w * 1024;

  f32x4 acc[4][4];
#pragma unroll
  for (int i = 0; i < 4; ++i)
#pragma unroll
    for (int j = 0; j < 4; ++j) acc[i][j] = (f32x4){0.f, 0.f, 0.f, 0.f};

  const __bf16* ap = As + (wm * 64 + (l & 15)) * 32 + (l >> 4) * 8;
  const __bf16* bp = Bs + (wn * 64 + (l & 15)) * 32 + (l >> 4) * 8;

  const int kIters = K >> 5;
  for (int kt = 0; kt < kIters; ++kt) {
    const int ko = kt * 32;
    async_copy16(Ag0 + ko, Al);
    async_copy16(Ag1 + ko, Al + 512);
    async_copy16(Bg0 + ko, Bl);
    async_copy16(Bg1 + ko, Bl + 512);
    __syncthreads();                 // drain vmcnt, LDS tiles ready

    bf16_8 af[4], bf[4];
#pragma unroll
    for (int i = 0; i < 4; ++i) af[i] = *(const bf16_8*)(ap + i * 16 * 32);
#pragma unroll
    for (int j = 0; j < 4; ++j) bf[j] = *(const bf16_8*)(bp + j * 16 * 32);
#pragma unroll
    for (int i = 0; i < 4; ++i)
#pragma unroll
      for (int j = 0; j < 4; ++j)
        acc[i][j] = __builtin_amdgcn_mfma_f32_16x16x32_bf16(af[i], bf[j], acc[i][j], 0, 0, 0);
    __syncthreads();                 // all reads done before next stage
  }

  // epilogue: C/D layout col = lane&15, row = (lane>>4)*4 + reg
  const int colb = n0 + wn * 64 + (l & 15);
  const int rowb = m0 + wm * 64 + (l >> 4) * 4;
#pragma unroll
  for (int j = 0; j < 4; ++j) {
    const int gc = colb + j * 16;
    if (gc >= N) continue;
    const float bj = bias[gc];
#pragma unroll
    for (int i = 0; i < 4; ++i) {
      const int gr0 = rowb + i * 16;
#pragma unroll
      for (int r = 0; r < 4; ++r) {
        const int gr = gr0 + r;
        if (gr >= M) continue;
        float v = acc[i][j][r] + bj;
        if (RELU) v = fmaxf(v, 0.0f);
        if (OUT_BF16) ((__bf16*)Cout)[(size_t)gr * N + gc] = (__bf16)v;
        else          ((float*)Cout)[(size_t)gr * N + gc] = v;
      }
    }
  }
}

// ---- weight transpose + bf16 convert: W(K,N) f32 -> WT(N,K) bf16 -----------
__global__ __launch_bounds__(256) void transpose_bf16(
    const float* __restrict__ W, __bf16* __restrict__ WT, int K, int N)
{
  __shared__ float t[32][33];
  const int b  = blockIdx.z;
  const int tx = threadIdx.x, ty = threadIdx.y;   // (32, 8)
  const int k0 = blockIdx.y * 32, n0 = blockIdx.x * 32;
  const float* Wb  = W  + (size_t)b * K * N;
  __bf16*      WTb = WT + (size_t)b * N * K;
#pragma unroll
  for (int r = 0; r < 4; ++r) {
    int kk = k0 + ty + r * 8;
    if (kk < K && n0 + tx < N) t[ty + r * 8][tx] = Wb[(size_t)kk * N + n0 + tx];
  }
  __syncthreads();
#pragma unroll
  for (int r = 0; r < 4; ++r) {
    int nn = n0 + ty + r * 8;
    if (nn < N && k0 + tx < K)
      WTb[(size_t)nn * K + k0 + tx] = (__bf16)t[tx][ty + r * 8];
  }
}

// ---- f32 -> bf16 elementwise convert ---------------------------------------
__global__ __launch_bounds__(256) void convert_bf16(
    const float* __restrict__ in, __bf16* __restrict__ out, int n)
{
  int i = blockIdx.x * 256 + threadIdx.x;
  if (i < n) out[i] = (__bf16)in[i];
}

// ---- iter-0 elementwise (init folded) --------------------------------------
__global__ __launch_bounds__(256) void ew_update0(
    const float* __restrict__ anchor, const float* __restrict__ fe,
    const float* __restrict__ snew_small, const float* __restrict__ cnew,
    float* __restrict__ s, float* __restrict__ c,
    __bf16* __restrict__ s_bf, __bf16* __restrict__ c_bf)
{
  int q = blockIdx.x * 256 + threadIdx.x;
  if (q >= BA * Dn) return;
  int ba = q >> 8;
  int n  = q & 255;
  float cn = cnew[q];
  float m = -3.402823466e38f;
  size_t base = (size_t)ba * Tn * Dn + n;
#pragma unroll
  for (int t = 0; t < Tn; ++t) {
    float sn = snew_small[t * Dn + n] * cn;
    m = fmaxf(m, sn);
    float v = kAlpha * anchor[t * Dn + n] + kBeta * sn;
    s[base + t * Dn]    = v;
    s_bf[base + t * Dn] = (__bf16)v;
  }
  float cv = kAlpha * fe[q] + kBeta * m;
  c[q]    = cv;
  c_bf[q] = (__bf16)cv;
}

// ---- per-iteration elementwise update --------------------------------------
__global__ __launch_bounds__(256) void ew_update(
    const float* __restrict__ snew, const float* __restrict__ cnew,
    float* __restrict__ s, float* __restrict__ c,
    __bf16* __restrict__ s_bf, __bf16* __restrict__ c_bf)
{
  int q = blockIdx.x * 256 + threadIdx.x;
  if (q >= BA * Dn) return;
  int ba = q >> 8;
  int n  = q & 255;
  float cn = cnew[q];
  float m = -3.402823466e38f;
  size_t base = (size_t)ba * Tn * Dn + n;
#pragma unroll
  for (int t = 0; t < Tn; ++t) {
    size_t idx = base + t * Dn;
    float sn = snew[idx] * cn;
    m = fmaxf(m, sn);
    float v = kAlpha * s[idx] + kBeta * sn;
    s[idx]    = v;
    s_bf[idx] = (__bf16)v;
  }
  float cv = kAlpha * c[q] + kBeta * m;
  c[q]    = cv;
  c_bf[q] = (__bf16)cv;
}

// ---- final epilogue --------------------------------------------------------
__global__ __launch_bounds__(256) void final_epilogue(
    const float* __restrict__ res, float* __restrict__ out)
{
  int q = blockIdx.x * 256 + threadIdx.x;
  if (q >= MR * 80) return;
  int r = q / 80;
  int j = q - r * 80;
  const float* row = res + (size_t)r * OUTn;

  float x  = row[2 * j];
  float y  = row[2 * j + 1];
  float av = row[160 + j];
  float bv = row[240 + j];
  float cv = row[320 + j];

  float ea = expf(av);
  float ec = expf(cv);
  float sh = sinhf(bv);
  float ch = coshf(bv);

  float* coords = out + MR;
  float* cov    = coords + (size_t)MR * 160;
  size_t cbase = (size_t)r * 160 + 2 * j;
  coords[cbase]     = x;
  coords[cbase + 1] = y;
  size_t vb = (size_t)r * 320 + j * 4;
  cov[vb + 0] = ea * ch * ec;
  cov[vb + 1] = sh * ec;
  cov[vb + 2] = sh * ec;
  cov[vb + 3] = ch / ea * ec;

  if (j == 0) out[r] = row[400];
}

// ---------------------------------------------------------------------------
extern "C" void kernel_launch(void* const* d_in, const int* in_sizes, int n_in,
                              void* d_out, int out_size, void* d_ws, size_t ws_size,
                              hipStream_t stream) {
  const float* fe     = (const float*)d_in[0];
  const float* anchor = (const float*)d_in[1];
  const float* sW1 = (const float*)d_in[2];
  const float* sb1 = (const float*)d_in[3];
  const float* sW2 = (const float*)d_in[4];
  const float* sb2 = (const float*)d_in[5];
  const float* cW1 = (const float*)d_in[6];
  const float* cb1 = (const float*)d_in[7];
  const float* cW2 = (const float*)d_in[8];
  const float* cb2 = (const float*)d_in[9];
  const float* dW1 = (const float*)d_in[10];
  const float* db1 = (const float*)d_in[11];
  const float* dW2 = (const float*)d_in[12];
  const float* db2 = (const float*)d_in[13];
  float* out = (float*)d_out;

  // ---- workspace layout (bytes); total ~209 MB (round-0 used 227 MB OK) ---
  char* p = (char*)d_ws;
  float* s_f    = (float*)(p + 0);                       // 50,331,648
  float* snew_f = (float*)(p + 50331648);                // 50,331,648
  float* res_f  = (float*)(p + 0);                       // alias s+snew (78.8MB)
  __bf16* hd_bf = (__bf16*)(p + 100663296);              // 50,331,648 (MRx512)
  __bf16* hs_bf = hd_bf;                                 // alias (MRx256)
  __bf16* s_bf  = (__bf16*)(p + 150994944);              // 25,165,824
  float* c_f    = (float*)(p + 176160768);               //  8,388,608
  float* cnew_f = (float*)(p + 184549376);               //  8,388,608
  __bf16* c_bf  = (__bf16*)(p + 192937984);              //  4,194,304
  __bf16* hc_bf = (__bf16*)(p + 197132288);              //  4,194,304
  __bf16* fe_bf = (__bf16*)(p + 201326592);              //  4,194,304
  __bf16* sWT1  = (__bf16*)(p + 205520896);              //    655,360
  __bf16* sWT2  = (__bf16*)(p + 206176256);
  __bf16* cWT1  = (__bf16*)(p + 206831616);
  __bf16* cWT2  = (__bf16*)(p + 207486976);
  __bf16* dWT1  = (__bf16*)(p + 208142336);              //    262,144
  __bf16* dWT2  = (__bf16*)(p + 208404480);              //    410,624
  __bf16* anc_bf  = (__bf16*)(p + 208815104);            //      3,072
  __bf16* hsm_bf  = (__bf16*)(p + 208818176);            //      3,072
  float* snewsm_f = (float*)(p + 208821248);             //      6,144

  auto gemm = [&](const __bf16* A, const __bf16* BT, const float* b, void* C,
                  int M, int N, int K, bool relu, bool outbf) {
    dim3 grid((N + 127) / 128, (M + 127) / 128);
    if (relu) {
      if (outbf) gemm_mfma<true,  true ><<<grid, 256, 0, stream>>>(A, BT, b, C, M, N, K);
      else       gemm_mfma<true,  false><<<grid, 256, 0, stream>>>(A, BT, b, C, M, N, K);
    } else {
      if (outbf) gemm_mfma<false, true ><<<grid, 256, 0, stream>>>(A, BT, b, C, M, N, K);
      else       gemm_mfma<false, false><<<grid, 256, 0, stream>>>(A, BT, b, C, M, N, K);
    }
  };

  // ---- weight prep: W(K,N) f32 -> WT(N,K) bf16 ----
  {
    dim3 blk(32, 8);
    dim3 g88(8, 8, NBn);
    transpose_bf16<<<g88, blk, 0, stream>>>(sW1, sWT1, Dn, Dn);
    transpose_bf16<<<g88, blk, 0, stream>>>(sW2, sWT2, Dn, Dn);
    transpose_bf16<<<g88, blk, 0, stream>>>(cW1, cWT1, Dn, Dn);
    transpose_bf16<<<g88, blk, 0, stream>>>(cW2, cWT2, Dn, Dn);
    transpose_bf16<<<dim3(16, 8, 1), blk, 0, stream>>>(dW1, dWT1, Dn, Hn);
    transpose_bf16<<<dim3(13, 16, 1), blk, 0, stream>>>(dW2, dWT2, Hn, OUTn);
  }
  convert_bf16<<<(BA * Dn + 255) / 256, 256, 0, stream>>>(fe, fe_bf, BA * Dn);
  convert_bf16<<<(Tn * Dn + 255) / 256, 256, 0, stream>>>(anchor, anc_bf, Tn * Dn);

  const int ewBlocks = (BA * Dn + 255) / 256;
  const size_t WKK = (size_t)Dn * Dn;

  // ---- iteration 0 (s-branch on 6 anchor rows only) ----
  gemm(anc_bf, sWT1, sb1, hsm_bf,   Tn, Dn, Dn, true,  true);
  gemm(hsm_bf, sWT2, sb2, snewsm_f, Tn, Dn, Dn, false, false);
  gemm(fe_bf,  cWT1, cb1, hc_bf,    BA, Dn, Dn, true,  true);
  gemm(hc_bf,  cWT2, cb2, cnew_f,   BA, Dn, Dn, false, false);
  ew_update0<<<ewBlocks, 256, 0, stream>>>(anchor, fe, snewsm_f, cnew_f,
                                           s_f, c_f, s_bf, c_bf);

  // ---- iterations 1..4 ----
  for (int i = 1; i < NBn; ++i) {
    gemm(s_bf,  sWT1 + i * WKK, sb1 + i * Dn, hs_bf,  MR, Dn, Dn, true,  true);
    gemm(hs_bf, sWT2 + i * WKK, sb2 + i * Dn, snew_f, MR, Dn, Dn, false, false);
    gemm(c_bf,  cWT1 + i * WKK, cb1 + i * Dn, hc_bf,  BA, Dn, Dn, true,  true);
    gemm(hc_bf, cWT2 + i * WKK, cb2 + i * Dn, cnew_f, BA, Dn, Dn, false, false);
    ew_update<<<ewBlocks, 256, 0, stream>>>(snew_f, cnew_f, s_f, c_f, s_bf, c_bf);
  }

  // ---- decoder ----
  gemm(s_bf,  dWT1, db1, hd_bf, MR, Hn,   Dn, true,  true);
  gemm(hd_bf, dWT2, db2, res_f, MR, OUTn, Hn, false, false);

  final_epilogue<<<(MR * 80 + 255) / 256, 256, 0, stream>>>(res_f, out);
}

// Round 3
// 720.160 us; speedup vs baseline: 3.5339x; 1.1209x over previous
//
#include <hip/hip_runtime.h>
#include <math.h>

// ---------------------------------------------------------------------------
// Round 3: traffic reduction.
//  - XCD-aware swizzle: all N-tiles of an M-tile on one XCD (A fetched once).
//  - bf16 master states + intermediates (fp32 only for res -> exp epilogue).
//  - vectorized bf16x8 elementwise update kernels.
// ---------------------------------------------------------------------------

constexpr int Tn  = 6;
constexpr int Dn  = 256;
constexpr int Hn  = 512;
constexpr int NBn = 5;
constexpr int OUTn = 401;
constexpr int BA  = 64 * 128;   // 8192
constexpr int MR  = BA * Tn;    // 49152
constexpr float kAlpha = 0.5f;
constexpr float kBeta  = 0.5f;

typedef __bf16 bf16_8 __attribute__((ext_vector_type(8)));
typedef float  f32x4  __attribute__((ext_vector_type(4)));

__device__ __forceinline__ void async_copy16(const __bf16* g, __bf16* l) {
  __builtin_amdgcn_global_load_lds(
      (const __attribute__((address_space(1))) void*)g,
      (__attribute__((address_space(3))) void*)l, 16, 0, 0);
}

// ---- GEMM: C = act(A @ BT^T + bias) ----------------------------------------
// A:(M,K) bf16 rm; BT:(N,K) bf16 rm; C:(M,N) fp32 or bf16. K % 32 == 0.
// XCD swizzle: linear block L -> xcd = L%8 owns a contiguous strip of logical
// tiles (n-fastest), so one M-tile's N-tiles share an XCD's L2.
template<bool RELU, bool OUT_BF16>
__global__ __launch_bounds__(256) void gemm_mfma(
    const __bf16* __restrict__ A, const __bf16* __restrict__ BT,
    const float* __restrict__ bias, void* __restrict__ Cout,
    int M, int N, int K)
{
  __shared__ __bf16 As[128 * 32];
  __shared__ __bf16 Bs[128 * 32];
  const int tid = threadIdx.x;
  const int l   = tid & 63;
  const int w   = tid >> 6;
  const int wm  = w >> 1, wn = w & 1;

  // XCD-aware tile remap
  const int GX = gridDim.x;
  const int total = GX * gridDim.y;
  const int L = blockIdx.y * GX + blockIdx.x;
  const int xcd = L & 7, pos = L >> 3;
  const int base = total >> 3, rem = total & 7;
  const int start = xcd * base + (xcd < rem ? xcd : rem);
  const int TL = start + pos;
  const int my = TL / GX;
  const int nx = TL - my * GX;
  const int m0 = my * 128;
  const int n0 = nx * 128;

  const int lrow = l >> 2;
  const int lk   = (l & 3) * 8;
  int ar0 = m0 + w * 32 + lrow;        if (ar0 > M - 1) ar0 = M - 1;
  int ar1 = m0 + w * 32 + 16 + lrow;   if (ar1 > M - 1) ar1 = M - 1;
  int br0 = n0 + w * 32 + lrow;        if (br0 > N - 1) br0 = N - 1;
  int br1 = n0 + w * 32 + 16 + lrow;   if (br1 > N - 1) br1 = N - 1;
  const __bf16* Ag0 = A  + (size_t)ar0 * K + lk;
  const __bf16* Ag1 = A  + (size_t)ar1 * K + lk;
  const __bf16* Bg0 = BT + (size_t)br0 * K + lk;
  const __bf16* Bg1 = BT + (size_t)br1 * K + lk;
  __bf16* Al = As + w * 1024;
  __bf16* Bl = Bs + w * 1024;

  f32x4 acc[4][4];
#pragma unroll
  for (int i = 0; i < 4; ++i)
#pragma unroll
    for (int j = 0; j < 4; ++j) acc[i][j] = (f32x4){0.f, 0.f, 0.f, 0.f};

  const __bf16* ap = As + (wm * 64 + (l & 15)) * 32 + (l >> 4) * 8;
  const __bf16* bp = Bs + (wn * 64 + (l & 15)) * 32 + (l >> 4) * 8;

  const int kIters = K >> 5;
  for (int kt = 0; kt < kIters; ++kt) {
    const int ko = kt * 32;
    async_copy16(Ag0 + ko, Al);
    async_copy16(Ag1 + ko, Al + 512);
    async_copy16(Bg0 + ko, Bl);
    async_copy16(Bg1 + ko, Bl + 512);
    __syncthreads();

    bf16_8 af[4], bf[4];
#pragma unroll
    for (int i = 0; i < 4; ++i) af[i] = *(const bf16_8*)(ap + i * 16 * 32);
#pragma unroll
    for (int j = 0; j < 4; ++j) bf[j] = *(const bf16_8*)(bp + j * 16 * 32);
#pragma unroll
    for (int i = 0; i < 4; ++i)
#pragma unroll
      for (int j = 0; j < 4; ++j)
        acc[i][j] = __builtin_amdgcn_mfma_f32_16x16x32_bf16(af[i], bf[j], acc[i][j], 0, 0, 0);
    __syncthreads();
  }

  const int colb = n0 + wn * 64 + (l & 15);
  const int rowb = m0 + wm * 64 + (l >> 4) * 4;
#pragma unroll
  for (int j = 0; j < 4; ++j) {
    const int gc = colb + j * 16;
    if (gc >= N) continue;
    const float bj = bias[gc];
#pragma unroll
    for (int i = 0; i < 4; ++i) {
      const int gr0 = rowb + i * 16;
#pragma unroll
      for (int r = 0; r < 4; ++r) {
        const int gr = gr0 + r;
        if (gr >= M) continue;
        float v = acc[i][j][r] + bj;
        if (RELU) v = fmaxf(v, 0.0f);
        if (OUT_BF16) ((__bf16*)Cout)[(size_t)gr * N + gc] = (__bf16)v;
        else          ((float*)Cout)[(size_t)gr * N + gc] = v;
      }
    }
  }
}

// ---- weight transpose + bf16 convert: W(K,N) f32 -> WT(N,K) bf16 -----------
__global__ __launch_bounds__(256) void transpose_bf16(
    const float* __restrict__ W, __bf16* __restrict__ WT, int K, int N)
{
  __shared__ float t[32][33];
  const int b  = blockIdx.z;
  const int tx = threadIdx.x, ty = threadIdx.y;
  const int k0 = blockIdx.y * 32, n0 = blockIdx.x * 32;
  const float* Wb  = W  + (size_t)b * K * N;
  __bf16*      WTb = WT + (size_t)b * N * K;
#pragma unroll
  for (int r = 0; r < 4; ++r) {
    int kk = k0 + ty + r * 8;
    if (kk < K && n0 + tx < N) t[ty + r * 8][tx] = Wb[(size_t)kk * N + n0 + tx];
  }
  __syncthreads();
#pragma unroll
  for (int r = 0; r < 4; ++r) {
    int nn = n0 + ty + r * 8;
    if (nn < N && k0 + tx < K)
      WTb[(size_t)nn * K + k0 + tx] = (__bf16)t[tx][ty + r * 8];
  }
}

__global__ __launch_bounds__(256) void convert_bf16(
    const float* __restrict__ in, __bf16* __restrict__ out, int n)
{
  int i = blockIdx.x * 256 + threadIdx.x;
  if (i < n) out[i] = (__bf16)in[i];
}

// ---- iter-0 elementwise (init folded), vectorized 8-wide -------------------
__global__ __launch_bounds__(256) void ew_update0(
    const float* __restrict__ anchor, const float* __restrict__ fe,
    const float* __restrict__ snewsm, const __bf16* __restrict__ cnew,
    __bf16* __restrict__ s, __bf16* __restrict__ c)
{
  int q = blockIdx.x * 256 + threadIdx.x;     // over BA*32
  if (q >= BA * 32) return;
  int ba = q >> 5;
  int dg = (q & 31) * 8;
  bf16_8 cn8 = *(const bf16_8*)(cnew + (size_t)ba * Dn + dg);
  float cn[8], m[8];
#pragma unroll
  for (int e = 0; e < 8; ++e) { cn[e] = (float)cn8[e]; m[e] = -3.402823466e38f; }
  size_t base = (size_t)ba * Tn * Dn + dg;
#pragma unroll
  for (int t = 0; t < Tn; ++t) {
    bf16_8 o8;
#pragma unroll
    for (int e = 0; e < 8; ++e) {
      float sn = snewsm[t * Dn + dg + e] * cn[e];
      m[e] = fmaxf(m[e], sn);
      o8[e] = (__bf16)(kAlpha * anchor[t * Dn + dg + e] + kBeta * sn);
    }
    *(bf16_8*)(s + base + t * Dn) = o8;
  }
  bf16_8 c8;
#pragma unroll
  for (int e = 0; e < 8; ++e)
    c8[e] = (__bf16)(kAlpha * fe[(size_t)ba * Dn + dg + e] + kBeta * m[e]);
  *(bf16_8*)(c + (size_t)ba * Dn + dg) = c8;
}

// ---- per-iteration elementwise update, vectorized 8-wide -------------------
__global__ __launch_bounds__(256) void ew_update(
    const __bf16* __restrict__ snew, const __bf16* __restrict__ cnew,
    __bf16* __restrict__ s, __bf16* __restrict__ c)
{
  int q = blockIdx.x * 256 + threadIdx.x;     // over BA*32
  if (q >= BA * 32) return;
  int ba = q >> 5;
  int dg = (q & 31) * 8;
  bf16_8 cn8 = *(const bf16_8*)(cnew + (size_t)ba * Dn + dg);
  float cn[8], m[8];
#pragma unroll
  for (int e = 0; e < 8; ++e) { cn[e] = (float)cn8[e]; m[e] = -3.402823466e38f; }
  size_t base = (size_t)ba * Tn * Dn + dg;
#pragma unroll
  for (int t = 0; t < Tn; ++t) {
    size_t idx = base + t * Dn;
    bf16_8 sn8 = *(const bf16_8*)(snew + idx);
    bf16_8 s8  = *(const bf16_8*)(s + idx);
    bf16_8 o8;
#pragma unroll
    for (int e = 0; e < 8; ++e) {
      float sn = (float)sn8[e] * cn[e];
      m[e] = fmaxf(m[e], sn);
      o8[e] = (__bf16)(kAlpha * (float)s8[e] + kBeta * sn);
    }
    *(bf16_8*)(s + idx) = o8;
  }
  bf16_8 c8 = *(const bf16_8*)(c + (size_t)ba * Dn + dg);
#pragma unroll
  for (int e = 0; e < 8; ++e)
    c8[e] = (__bf16)(kAlpha * (float)c8[e] + kBeta * m[e]);
  *(bf16_8*)(c + (size_t)ba * Dn + dg) = c8;
}

// ---- final epilogue --------------------------------------------------------
__global__ __launch_bounds__(256) void final_epilogue(
    const float* __restrict__ res, float* __restrict__ out)
{
  int q = blockIdx.x * 256 + threadIdx.x;
  if (q >= MR * 80) return;
  int r = q / 80;
  int j = q - r * 80;
  const float* row = res + (size_t)r * OUTn;

  float x  = row[2 * j];
  float y  = row[2 * j + 1];
  float av = row[160 + j];
  float bv = row[240 + j];
  float cv = row[320 + j];

  float ea = expf(av);
  float ec = expf(cv);
  float sh = sinhf(bv);
  float ch = coshf(bv);

  float* coords = out + MR;
  float* cov    = coords + (size_t)MR * 160;
  size_t cbase = (size_t)r * 160 + 2 * j;
  coords[cbase]     = x;
  coords[cbase + 1] = y;
  size_t vb = (size_t)r * 320 + j * 4;
  cov[vb + 0] = ea * ch * ec;
  cov[vb + 1] = sh * ec;
  cov[vb + 2] = sh * ec;
  cov[vb + 3] = ch / ea * ec;

  if (j == 0) out[r] = row[400];
}

// ---------------------------------------------------------------------------
extern "C" void kernel_launch(void* const* d_in, const int* in_sizes, int n_in,
                              void* d_out, int out_size, void* d_ws, size_t ws_size,
                              hipStream_t stream) {
  const float* fe     = (const float*)d_in[0];
  const float* anchor = (const float*)d_in[1];
  const float* sW1 = (const float*)d_in[2];
  const float* sb1 = (const float*)d_in[3];
  const float* sW2 = (const float*)d_in[4];
  const float* sb2 = (const float*)d_in[5];
  const float* cW1 = (const float*)d_in[6];
  const float* cb1 = (const float*)d_in[7];
  const float* cW2 = (const float*)d_in[8];
  const float* cb2 = (const float*)d_in[9];
  const float* dW1 = (const float*)d_in[10];
  const float* db1 = (const float*)d_in[11];
  const float* dW2 = (const float*)d_in[12];
  const float* db2 = (const float*)d_in[13];
  float* out = (float*)d_out;

  // ---- workspace layout (bytes), total ~200 MB ----
  char* p = (char*)d_ws;
  __bf16* s_bf    = (__bf16*)(p + 0);            // 25,165,824
  __bf16* snew_bf = (__bf16*)(p + 25165824);     // 25,165,824
  __bf16* hd_bf   = (__bf16*)(p + 50331648);     // 50,331,648 (MRxHn)
  __bf16* hs_bf   = hd_bf;                       // alias (MRxDn)
  float*  res_f   = (float* )(p + 100663296);    // 78,839,808
  __bf16* c_bf    = (__bf16*)(p + 179503104);    //  4,194,304
  __bf16* cnew_bf = (__bf16*)(p + 183697408);    //  4,194,304
  __bf16* hc_bf   = (__bf16*)(p + 187891712);    //  4,194,304
  __bf16* fe_bf   = (__bf16*)(p + 192086016);    //  4,194,304
  __bf16* sWT1    = (__bf16*)(p + 196280320);    //    655,360 each
  __bf16* sWT2    = (__bf16*)(p + 196935680);
  __bf16* cWT1    = (__bf16*)(p + 197591040);
  __bf16* cWT2    = (__bf16*)(p + 198246400);
  __bf16* dWT1    = (__bf16*)(p + 198901760);    //    262,144
  __bf16* dWT2    = (__bf16*)(p + 199163904);    //    410,624
  __bf16* anc_bf  = (__bf16*)(p + 199574528);    //      3,072
  __bf16* hsm_bf  = (__bf16*)(p + 199577600);    //      3,072
  float*  snewsm_f= (float* )(p + 199580672);    //      6,144

  auto gemm = [&](const __bf16* A, const __bf16* BT, const float* b, void* C,
                  int M, int N, int K, bool relu, bool outbf) {
    dim3 grid((N + 127) / 128, (M + 127) / 128);
    if (relu) {
      if (outbf) gemm_mfma<true,  true ><<<grid, 256, 0, stream>>>(A, BT, b, C, M, N, K);
      else       gemm_mfma<true,  false><<<grid, 256, 0, stream>>>(A, BT, b, C, M, N, K);
    } else {
      if (outbf) gemm_mfma<false, true ><<<grid, 256, 0, stream>>>(A, BT, b, C, M, N, K);
      else       gemm_mfma<false, false><<<grid, 256, 0, stream>>>(A, BT, b, C, M, N, K);
    }
  };

  // ---- weight prep ----
  {
    dim3 blk(32, 8);
    dim3 g88(8, 8, NBn);
    transpose_bf16<<<g88, blk, 0, stream>>>(sW1, sWT1, Dn, Dn);
    transpose_bf16<<<g88, blk, 0, stream>>>(sW2, sWT2, Dn, Dn);
    transpose_bf16<<<g88, blk, 0, stream>>>(cW1, cWT1, Dn, Dn);
    transpose_bf16<<<g88, blk, 0, stream>>>(cW2, cWT2, Dn, Dn);
    transpose_bf16<<<dim3(16, 8, 1), blk, 0, stream>>>(dW1, dWT1, Dn, Hn);
    transpose_bf16<<<dim3(13, 16, 1), blk, 0, stream>>>(dW2, dWT2, Hn, OUTn);
  }
  convert_bf16<<<(BA * Dn + 255) / 256, 256, 0, stream>>>(fe, fe_bf, BA * Dn);
  convert_bf16<<<(Tn * Dn + 255) / 256, 256, 0, stream>>>(anchor, anc_bf, Tn * Dn);

  const int ewBlocks = (BA * 32 + 255) / 256;
  const size_t WKK = (size_t)Dn * Dn;

  // ---- iteration 0 (s-branch on 6 anchor rows only) ----
  gemm(anc_bf, sWT1, sb1, hsm_bf,   Tn, Dn, Dn, true,  true);
  gemm(hsm_bf, sWT2, sb2, snewsm_f, Tn, Dn, Dn, false, false);
  gemm(fe_bf,  cWT1, cb1, hc_bf,    BA, Dn, Dn, true,  true);
  gemm(hc_bf,  cWT2, cb2, cnew_bf,  BA, Dn, Dn, false, true);
  ew_update0<<<ewBlocks, 256, 0, stream>>>(anchor, fe, snewsm_f, cnew_bf,
                                           s_bf, c_bf);

  // ---- iterations 1..4 ----
  for (int i = 1; i < NBn; ++i) {
    gemm(s_bf,  sWT1 + i * WKK, sb1 + i * Dn, hs_bf,   MR, Dn, Dn, true,  true);
    gemm(hs_bf, sWT2 + i * WKK, sb2 + i * Dn, snew_bf, MR, Dn, Dn, false, true);
    gemm(c_bf,  cWT1 + i * WKK, cb1 + i * Dn, hc_bf,   BA, Dn, Dn, true,  true);
    gemm(hc_bf, cWT2 + i * WKK, cb2 + i * Dn, cnew_bf, BA, Dn, Dn, false, true);
    ew_update<<<ewBlocks, 256, 0, stream>>>(snew_bf, cnew_bf, s_bf, c_bf);
  }

  // ---- decoder ----
  gemm(s_bf,  dWT1, db1, hd_bf, MR, Hn,   Dn, true,  true);
  gemm(hd_bf, dWT2, db2, res_f, MR, OUTn, Hn, false, false);

  final_epilogue<<<(MR * 80 + 255) / 256, 256, 0, stream>>>(res_f, out);
}

// Round 4
// 517.075 us; speedup vs baseline: 4.9218x; 1.3928x over previous
//
#include <hip/hip_runtime.h>
#include <math.h>

// ---------------------------------------------------------------------------
// Round 4:
//  - decoder2_fused: BM=32 x BN=512 full-row blocks; cov epilogue fused via
//    LDS (res never hits HBM). Saves ~220 MB of decoder-tail traffic.
//  - generic gemm bf16 path: LDS-staged epilogue -> full-line uint4 stores
//    (kills partial-line write amplification seen on decoder-2: 1.84x).
// ---------------------------------------------------------------------------

constexpr int Tn  = 6;
constexpr int Dn  = 256;
constexpr int Hn  = 512;
constexpr int NBn = 5;
constexpr int OUTn = 401;
constexpr int BA  = 64 * 128;   // 8192
constexpr int MR  = BA * Tn;    // 49152
constexpr float kAlpha = 0.5f;
constexpr float kBeta  = 0.5f;

typedef __bf16 bf16_8 __attribute__((ext_vector_type(8)));
typedef float  f32x4  __attribute__((ext_vector_type(4)));

__device__ __forceinline__ void async_copy16(const __bf16* g, __bf16* l) {
  __builtin_amdgcn_global_load_lds(
      (const __attribute__((address_space(1))) void*)g,
      (__attribute__((address_space(3))) void*)l, 16, 0, 0);
}

// ---- generic GEMM: C = act(A @ BT^T + bias) --------------------------------
// A:(M,K) bf16 rm; BT:(N,K) bf16 rm. OUT_BF16 path requires N % 128 == 0.
template<bool RELU, bool OUT_BF16>
__global__ __launch_bounds__(256) void gemm_mfma(
    const __bf16* __restrict__ A, const __bf16* __restrict__ BT,
    const float* __restrict__ bias, void* __restrict__ Cout,
    int M, int N, int K)
{
  // union: K-loop tiles (16 KB) / epilogue C tile 128 x (128+8pad) bf16 (34 KB)
  __shared__ __align__(16) char smem[128 * 136 * 2];
  __bf16* As = (__bf16*)smem;          // 128*32
  __bf16* Bs = As + 128 * 32;          // 128*32

  const int tid = threadIdx.x;
  const int l   = tid & 63;
  const int w   = tid >> 6;
  const int wm  = w >> 1, wn = w & 1;

  // XCD-aware tile remap (n-fastest strips per XCD)
  const int GX = gridDim.x;
  const int total = GX * gridDim.y;
  const int L = blockIdx.y * GX + blockIdx.x;
  const int xcd = L & 7, pos = L >> 3;
  const int base = total >> 3, rem = total & 7;
  const int start = xcd * base + (xcd < rem ? xcd : rem);
  const int TL = start + pos;
  const int my = TL / GX;
  const int nx = TL - my * GX;
  const int m0 = my * 128;
  const int n0 = nx * 128;

  const int lrow = l >> 2;
  const int lk   = (l & 3) * 8;
  int ar0 = m0 + w * 32 + lrow;        if (ar0 > M - 1) ar0 = M - 1;
  int ar1 = m0 + w * 32 + 16 + lrow;   if (ar1 > M - 1) ar1 = M - 1;
  int br0 = n0 + w * 32 + lrow;        if (br0 > N - 1) br0 = N - 1;
  int br1 = n0 + w * 32 + 16 + lrow;   if (br1 > N - 1) br1 = N - 1;
  const __bf16* Ag0 = A  + (size_t)ar0 * K + lk;
  const __bf16* Ag1 = A  + (size_t)ar1 * K + lk;
  const __bf16* Bg0 = BT + (size_t)br0 * K + lk;
  const __bf16* Bg1 = BT + (size_t)br1 * K + lk;
  __bf16* Al = As + w * 1024;
  __bf16* Bl = Bs + w * 1024;

  f32x4 acc[4][4];
#pragma unroll
  for (int i = 0; i < 4; ++i)
#pragma unroll
    for (int j = 0; j < 4; ++j) acc[i][j] = (f32x4){0.f, 0.f, 0.f, 0.f};

  const __bf16* ap = As + (wm * 64 + (l & 15)) * 32 + (l >> 4) * 8;
  const __bf16* bp = Bs + (wn * 64 + (l & 15)) * 32 + (l >> 4) * 8;

  const int kIters = K >> 5;
  for (int kt = 0; kt < kIters; ++kt) {
    const int ko = kt * 32;
    async_copy16(Ag0 + ko, Al);
    async_copy16(Ag1 + ko, Al + 512);
    async_copy16(Bg0 + ko, Bl);
    async_copy16(Bg1 + ko, Bl + 512);
    __syncthreads();

    bf16_8 af[4], bf[4];
#pragma unroll
    for (int i = 0; i < 4; ++i) af[i] = *(const bf16_8*)(ap + i * 16 * 32);
#pragma unroll
    for (int j = 0; j < 4; ++j) bf[j] = *(const bf16_8*)(bp + j * 16 * 32);
#pragma unroll
    for (int i = 0; i < 4; ++i)
#pragma unroll
      for (int j = 0; j < 4; ++j)
        acc[i][j] = __builtin_amdgcn_mfma_f32_16x16x32_bf16(af[i], bf[j], acc[i][j], 0, 0, 0);
    __syncthreads();
  }

  const int colb = n0 + wn * 64 + (l & 15);
  const int rowb = m0 + wm * 64 + (l >> 4) * 4;

  if (OUT_BF16) {
    // stage C tile to LDS (stride 136 elems = 272 B: 16B-aligned rows,
    // bank drift 4/row -> <=2-way write aliasing), then full-line stores.
    __bf16* Cs = (__bf16*)smem;
    const int lrb = wm * 64 + (l >> 4) * 4;
    const int lcb = wn * 64 + (l & 15);
#pragma unroll
    for (int j = 0; j < 4; ++j) {
      const float bj = bias[colb + j * 16];
#pragma unroll
      for (int i = 0; i < 4; ++i) {
#pragma unroll
        for (int r = 0; r < 4; ++r) {
          float v = acc[i][j][r] + bj;
          if (RELU) v = fmaxf(v, 0.0f);
          Cs[(lrb + i * 16 + r) * 136 + lcb + j * 16] = (__bf16)v;
        }
      }
    }
    __syncthreads();
    __bf16* Cg = (__bf16*)Cout;
#pragma unroll
    for (int it = 0; it < 8; ++it) {
      const int idx = it * 256 + tid;      // 2048 x 16B chunks
      const int row = idx >> 4, c16 = idx & 15;
      const int gr = m0 + row;
      if (gr < M) {
        uint4 v = *(const uint4*)(Cs + row * 136 + c16 * 8);
        *(uint4*)(Cg + (size_t)gr * N + n0 + c16 * 8) = v;
      }
    }
  } else {
#pragma unroll
    for (int j = 0; j < 4; ++j) {
      const int gc = colb + j * 16;
      if (gc >= N) continue;
      const float bj = bias[gc];
#pragma unroll
      for (int i = 0; i < 4; ++i) {
        const int gr0 = rowb + i * 16;
#pragma unroll
        for (int r = 0; r < 4; ++r) {
          const int gr = gr0 + r;
          if (gr >= M) continue;
          float v = acc[i][j][r] + bj;
          if (RELU) v = fmaxf(v, 0.0f);
          ((float*)Cout)[(size_t)gr * N + gc] = v;
        }
      }
    }
  }
}

// ---- fused decoder-2 + covariance epilogue ---------------------------------
// A = hd (MR,512) bf16; BT = dWT2 (401 valid rows, 512) bf16; bias = db2(401).
// Block: BM=32 rows x all 512 cols (401 valid); wave w owns cols w*128..+127.
__global__ __launch_bounds__(256) void decoder2_fused(
    const __bf16* __restrict__ A, const __bf16* __restrict__ BT,
    const float* __restrict__ bias, float* __restrict__ out)
{
  // union: {A tile 2KB | B tile 32KB} vs mid[32][241] fp32 (30.8 KB)
  __shared__ __align__(16) char smem[2048 + 32768];
  __bf16* Asm = (__bf16*)smem;
  __bf16* Bsm = (__bf16*)(smem + 2048);
  float*  mid = (float*)smem;

  const int tid = threadIdx.x;
  const int l = tid & 63, w = tid >> 6;
  const int m0 = blockIdx.x * 32;

  // A staging: waves 0-1 cover 128 x 16B chunks (32 rows x 32 k)
  const int ach = w * 64 + l;
  const __bf16* Ag = A + (size_t)(m0 + (ach >> 2)) * 512 + (ach & 3) * 8;
  __bf16* Al = Asm + ach * 8;

  f32x4 acc[2][8];
#pragma unroll
  for (int i = 0; i < 2; ++i)
#pragma unroll
    for (int j = 0; j < 8; ++j) acc[i][j] = (f32x4){0.f, 0.f, 0.f, 0.f};

  const __bf16* ap0 = Asm + ((l & 15)) * 32 + (l >> 4) * 8;
  const __bf16* ap1 = Asm + ((l & 15) + 16) * 32 + (l >> 4) * 8;
  const __bf16* bp  = Bsm + (size_t)(w * 128 + (l & 15)) * 32 + (l >> 4) * 8;

  for (int kt = 0; kt < 16; ++kt) {
    const int ko = kt * 32;
    if (w < 2) async_copy16(Ag + ko, Al);
#pragma unroll
    for (int b = 0; b < 8; ++b) {
      const int ch = b * 256 + tid;          // 2048 chunks: 512 rows x 4
      const int row = ch >> 2;
      const int srow = row < OUTn ? row : OUTn - 1;   // clamp pad rows
      async_copy16(BT + (size_t)srow * 512 + (ch & 3) * 8 + ko, Bsm + ch * 8);
    }
    __syncthreads();
    bf16_8 a0 = *(const bf16_8*)ap0;
    bf16_8 a1 = *(const bf16_8*)ap1;
#pragma unroll
    for (int jj = 0; jj < 8; ++jj) {
      bf16_8 bfr = *(const bf16_8*)(bp + jj * 16 * 32);
      acc[0][jj] = __builtin_amdgcn_mfma_f32_16x16x32_bf16(a0, bfr, acc[0][jj], 0, 0, 0);
      acc[1][jj] = __builtin_amdgcn_mfma_f32_16x16x32_bf16(a1, bfr, acc[1][jj], 0, 0, 0);
    }
    __syncthreads();
  }

  // scatter: coords/probas direct, av/bv/cv bands into LDS mid
  const int colb = w * 128 + (l & 15);
  const int rowb = (l >> 4) * 4;
#pragma unroll
  for (int jj = 0; jj < 8; ++jj) {
    const int gc = colb + jj * 16;
    if (gc > 400) continue;
    const float bj = bias[gc];
#pragma unroll
    for (int ii = 0; ii < 2; ++ii) {
#pragma unroll
      for (int r = 0; r < 4; ++r) {
        const int lr = rowb + ii * 16 + r;
        const int gr = m0 + lr;
        const float v = acc[ii][jj][r] + bj;
        if (gc < 160)      out[(size_t)MR + (size_t)gr * 160 + gc] = v;
        else if (gc < 400) mid[lr * 241 + (gc - 160)] = v;
        else               out[gr] = v;          // probas (col 400)
      }
    }
  }
  __syncthreads();

  // covariance: 32 rows x 80 j-groups = 2560 items
  float* cov = out + MR + (size_t)MR * 160;
#pragma unroll
  for (int it = 0; it < 10; ++it) {
    const int q = it * 256 + tid;
    const int r = q / 80;
    const int j = q - r * 80;
    const int gr = m0 + r;
    const float av = mid[r * 241 + j];
    const float bv = mid[r * 241 + 80 + j];
    const float cv = mid[r * 241 + 160 + j];
    const float ea = expf(av);
    const float ec = expf(cv);
    const float sh = sinhf(bv);
    const float ch = coshf(bv);
    f32x4 c4 = { ea * ch * ec, sh * ec, sh * ec, ch / ea * ec };
    *(f32x4*)(cov + (size_t)gr * 320 + 4 * j) = c4;
  }
}

// ---- weight transpose + bf16 convert: W(K,N) f32 -> WT(N,K) bf16 -----------
__global__ __launch_bounds__(256) void transpose_bf16(
    const float* __restrict__ W, __bf16* __restrict__ WT, int K, int N)
{
  __shared__ float t[32][33];
  const int b  = blockIdx.z;
  const int tx = threadIdx.x, ty = threadIdx.y;
  const int k0 = blockIdx.y * 32, n0 = blockIdx.x * 32;
  const float* Wb  = W  + (size_t)b * K * N;
  __bf16*      WTb = WT + (size_t)b * N * K;
#pragma unroll
  for (int r = 0; r < 4; ++r) {
    int kk = k0 + ty + r * 8;
    if (kk < K && n0 + tx < N) t[ty + r * 8][tx] = Wb[(size_t)kk * N + n0 + tx];
  }
  __syncthreads();
#pragma unroll
  for (int r = 0; r < 4; ++r) {
    int nn = n0 + ty + r * 8;
    if (nn < N && k0 + tx < K)
      WTb[(size_t)nn * K + k0 + tx] = (__bf16)t[tx][ty + r * 8];
  }
}

__global__ __launch_bounds__(256) void convert_bf16(
    const float* __restrict__ in, __bf16* __restrict__ out, int n)
{
  int i = blockIdx.x * 256 + threadIdx.x;
  if (i < n) out[i] = (__bf16)in[i];
}

// ---- iter-0 elementwise (init folded), vectorized 8-wide -------------------
__global__ __launch_bounds__(256) void ew_update0(
    const float* __restrict__ anchor, const float* __restrict__ fe,
    const float* __restrict__ snewsm, const __bf16* __restrict__ cnew,
    __bf16* __restrict__ s, __bf16* __restrict__ c)
{
  int q = blockIdx.x * 256 + threadIdx.x;     // over BA*32
  if (q >= BA * 32) return;
  int ba = q >> 5;
  int dg = (q & 31) * 8;
  bf16_8 cn8 = *(const bf16_8*)(cnew + (size_t)ba * Dn + dg);
  float cn[8], m[8];
#pragma unroll
  for (int e = 0; e < 8; ++e) { cn[e] = (float)cn8[e]; m[e] = -3.402823466e38f; }
  size_t base = (size_t)ba * Tn * Dn + dg;
#pragma unroll
  for (int t = 0; t < Tn; ++t) {
    bf16_8 o8;
#pragma unroll
    for (int e = 0; e < 8; ++e) {
      float sn = snewsm[t * Dn + dg + e] * cn[e];
      m[e] = fmaxf(m[e], sn);
      o8[e] = (__bf16)(kAlpha * anchor[t * Dn + dg + e] + kBeta * sn);
    }
    *(bf16_8*)(s + base + t * Dn) = o8;
  }
  bf16_8 c8;
#pragma unroll
  for (int e = 0; e < 8; ++e)
    c8[e] = (__bf16)(kAlpha * fe[(size_t)ba * Dn + dg + e] + kBeta * m[e]);
  *(bf16_8*)(c + (size_t)ba * Dn + dg) = c8;
}

// ---- per-iteration elementwise update, vectorized 8-wide -------------------
__global__ __launch_bounds__(256) void ew_update(
    const __bf16* __restrict__ snew, const __bf16* __restrict__ cnew,
    __bf16* __restrict__ s, __bf16* __restrict__ c)
{
  int q = blockIdx.x * 256 + threadIdx.x;     // over BA*32
  if (q >= BA * 32) return;
  int ba = q >> 5;
  int dg = (q & 31) * 8;
  bf16_8 cn8 = *(const bf16_8*)(cnew + (size_t)ba * Dn + dg);
  float cn[8], m[8];
#pragma unroll
  for (int e = 0; e < 8; ++e) { cn[e] = (float)cn8[e]; m[e] = -3.402823466e38f; }
  size_t base = (size_t)ba * Tn * Dn + dg;
#pragma unroll
  for (int t = 0; t < Tn; ++t) {
    size_t idx = base + t * Dn;
    bf16_8 sn8 = *(const bf16_8*)(snew + idx);
    bf16_8 s8  = *(const bf16_8*)(s + idx);
    bf16_8 o8;
#pragma unroll
    for (int e = 0; e < 8; ++e) {
      float sn = (float)sn8[e] * cn[e];
      m[e] = fmaxf(m[e], sn);
      o8[e] = (__bf16)(kAlpha * (float)s8[e] + kBeta * sn);
    }
    *(bf16_8*)(s + idx) = o8;
  }
  bf16_8 c8 = *(const bf16_8*)(c + (size_t)ba * Dn + dg);
#pragma unroll
  for (int e = 0; e < 8; ++e)
    c8[e] = (__bf16)(kAlpha * (float)c8[e] + kBeta * m[e]);
  *(bf16_8*)(c + (size_t)ba * Dn + dg) = c8;
}

// ---------------------------------------------------------------------------
extern "C" void kernel_launch(void* const* d_in, const int* in_sizes, int n_in,
                              void* d_out, int out_size, void* d_ws, size_t ws_size,
                              hipStream_t stream) {
  const float* fe     = (const float*)d_in[0];
  const float* anchor = (const float*)d_in[1];
  const float* sW1 = (const float*)d_in[2];
  const float* sb1 = (const float*)d_in[3];
  const float* sW2 = (const float*)d_in[4];
  const float* sb2 = (const float*)d_in[5];
  const float* cW1 = (const float*)d_in[6];
  const float* cb1 = (const float*)d_in[7];
  const float* cW2 = (const float*)d_in[8];
  const float* cb2 = (const float*)d_in[9];
  const float* dW1 = (const float*)d_in[10];
  const float* db1 = (const float*)d_in[11];
  const float* dW2 = (const float*)d_in[12];
  const float* db2 = (const float*)d_in[13];
  float* out = (float*)d_out;

  // ---- workspace layout (bytes), total ~121 MB ----
  char* p = (char*)d_ws;
  __bf16* s_bf    = (__bf16*)(p + 0);            // 25,165,824
  __bf16* snew_bf = (__bf16*)(p + 25165824);     // 25,165,824
  __bf16* hd_bf   = (__bf16*)(p + 50331648);     // 50,331,648 (MRxHn)
  __bf16* hs_bf   = hd_bf;                       // alias (MRxDn)
  __bf16* c_bf    = (__bf16*)(p + 100663296);    //  4,194,304
  __bf16* cnew_bf = (__bf16*)(p + 104857600);    //  4,194,304
  __bf16* hc_bf   = (__bf16*)(p + 109051904);    //  4,194,304
  __bf16* fe_bf   = (__bf16*)(p + 113246208);    //  4,194,304
  __bf16* sWT1    = (__bf16*)(p + 117440512);    //    655,360 each
  __bf16* sWT2    = (__bf16*)(p + 118095872);
  __bf16* cWT1    = (__bf16*)(p + 118751232);
  __bf16* cWT2    = (__bf16*)(p + 119406592);
  __bf16* dWT1    = (__bf16*)(p + 120061952);    //    524,288
  __bf16* dWT2    = (__bf16*)(p + 120586240);    //    410,624
  __bf16* anc_bf  = (__bf16*)(p + 120996864);    //      3,072
  __bf16* hsm_bf  = (__bf16*)(p + 120999936);    //      3,072
  float*  snewsm_f= (float* )(p + 121003008);    //      6,144

  auto gemm = [&](const __bf16* A, const __bf16* BT, const float* b, void* C,
                  int M, int N, int K, bool relu, bool outbf) {
    dim3 grid((N + 127) / 128, (M + 127) / 128);
    if (relu) {
      if (outbf) gemm_mfma<true,  true ><<<grid, 256, 0, stream>>>(A, BT, b, C, M, N, K);
      else       gemm_mfma<true,  false><<<grid, 256, 0, stream>>>(A, BT, b, C, M, N, K);
    } else {
      if (outbf) gemm_mfma<false, true ><<<grid, 256, 0, stream>>>(A, BT, b, C, M, N, K);
      else       gemm_mfma<false, false><<<grid, 256, 0, stream>>>(A, BT, b, C, M, N, K);
    }
  };

  // ---- weight prep ----
  {
    dim3 blk(32, 8);
    dim3 g88(8, 8, NBn);
    transpose_bf16<<<g88, blk, 0, stream>>>(sW1, sWT1, Dn, Dn);
    transpose_bf16<<<g88, blk, 0, stream>>>(sW2, sWT2, Dn, Dn);
    transpose_bf16<<<g88, blk, 0, stream>>>(cW1, cWT1, Dn, Dn);
    transpose_bf16<<<g88, blk, 0, stream>>>(cW2, cWT2, Dn, Dn);
    transpose_bf16<<<dim3(16, 8, 1), blk, 0, stream>>>(dW1, dWT1, Dn, Hn);
    transpose_bf16<<<dim3(13, 16, 1), blk, 0, stream>>>(dW2, dWT2, Hn, OUTn);
  }
  convert_bf16<<<(BA * Dn + 255) / 256, 256, 0, stream>>>(fe, fe_bf, BA * Dn);
  convert_bf16<<<(Tn * Dn + 255) / 256, 256, 0, stream>>>(anchor, anc_bf, Tn * Dn);

  const int ewBlocks = (BA * 32 + 255) / 256;
  const size_t WKK = (size_t)Dn * Dn;

  // ---- iteration 0 (s-branch on 6 anchor rows only) ----
  gemm(anc_bf, sWT1, sb1, hsm_bf,   Tn, Dn, Dn, true,  true);
  gemm(hsm_bf, sWT2, sb2, snewsm_f, Tn, Dn, Dn, false, false);
  gemm(fe_bf,  cWT1, cb1, hc_bf,    BA, Dn, Dn, true,  true);
  gemm(hc_bf,  cWT2, cb2, cnew_bf,  BA, Dn, Dn, false, true);
  ew_update0<<<ewBlocks, 256, 0, stream>>>(anchor, fe, snewsm_f, cnew_bf,
                                           s_bf, c_bf);

  // ---- iterations 1..4 ----
  for (int i = 1; i < NBn; ++i) {
    gemm(s_bf,  sWT1 + i * WKK, sb1 + i * Dn, hs_bf,   MR, Dn, Dn, true,  true);
    gemm(hs_bf, sWT2 + i * WKK, sb2 + i * Dn, snew_bf, MR, Dn, Dn, false, true);
    gemm(c_bf,  cWT1 + i * WKK, cb1 + i * Dn, hc_bf,   BA, Dn, Dn, true,  true);
    gemm(hc_bf, cWT2 + i * WKK, cb2 + i * Dn, cnew_bf, BA, Dn, Dn, false, true);
    ew_update<<<ewBlocks, 256, 0, stream>>>(snew_bf, cnew_bf, s_bf, c_bf);
  }

  // ---- decoder: GEMM1 -> hd; GEMM2 fused with covariance epilogue ----
  gemm(s_bf, dWT1, db1, hd_bf, MR, Hn, Dn, true, true);
  decoder2_fused<<<dim3(MR / 32), 256, 0, stream>>>(hd_bf, dWT2, db2, out);
}

// Round 5
// 441.146 us; speedup vs baseline: 5.7690x; 1.1721x over previous
//
#include <hip/hip_runtime.h>
#include <math.h>

// ---------------------------------------------------------------------------
// Round 5: kernel fusion.
//  - mlp2_c: 2-layer c-MLP in one kernel (h in LDS, pre-tiled).
//  - mlp2_s: 2-layer s-MLP + elementwise update fused. BM=96 = 16 complete
//    (b,a) groups (T=6), so max-over-T is block-local. snew/hs never in HBM.
//  - decoder2_fused v2: BM=128 x 512 threads (4x less B re-staging, which was
//    the measured L2 bottleneck), cov epilogue in 4x32-row LDS sub-passes.
// ---------------------------------------------------------------------------

constexpr int Tn  = 6;
constexpr int Dn  = 256;
constexpr int Hn  = 512;
constexpr int NBn = 5;
constexpr int OUTn = 401;
constexpr int BA  = 8192;
constexpr int MR  = 49152;
constexpr float kAlpha = 0.5f;
constexpr float kBeta  = 0.5f;

typedef __bf16 bf16_8 __attribute__((ext_vector_type(8)));
typedef float  f32x4  __attribute__((ext_vector_type(4)));

__device__ __forceinline__ void async_copy16(const __bf16* g, __bf16* l) {
  __builtin_amdgcn_global_load_lds(
      (const __attribute__((address_space(1))) void*)g,
      (__attribute__((address_space(3))) void*)l, 16, 0, 0);
}

// ---- generic GEMM (kept for tiny anchor GEMMs + decoder-1) -----------------
template<bool RELU, bool OUT_BF16>
__global__ __launch_bounds__(256) void gemm_mfma(
    const __bf16* __restrict__ A, const __bf16* __restrict__ BT,
    const float* __restrict__ bias, void* __restrict__ Cout,
    int M, int N, int K)
{
  __shared__ __align__(16) char smem[128 * 136 * 2];
  __bf16* As = (__bf16*)smem;
  __bf16* Bs = As + 128 * 32;

  const int tid = threadIdx.x;
  const int l   = tid & 63;
  const int w   = tid >> 6;
  const int wm  = w >> 1, wn = w & 1;

  const int GX = gridDim.x;
  const int total = GX * gridDim.y;
  const int L = blockIdx.y * GX + blockIdx.x;
  const int xcd = L & 7, pos = L >> 3;
  const int base = total >> 3, rem = total & 7;
  const int start = xcd * base + (xcd < rem ? xcd : rem);
  const int TL = start + pos;
  const int my = TL / GX;
  const int nx = TL - my * GX;
  const int m0 = my * 128;
  const int n0 = nx * 128;

  const int lrow = l >> 2;
  const int lk   = (l & 3) * 8;
  int ar0 = m0 + w * 32 + lrow;        if (ar0 > M - 1) ar0 = M - 1;
  int ar1 = m0 + w * 32 + 16 + lrow;   if (ar1 > M - 1) ar1 = M - 1;
  int br0 = n0 + w * 32 + lrow;        if (br0 > N - 1) br0 = N - 1;
  int br1 = n0 + w * 32 + 16 + lrow;   if (br1 > N - 1) br1 = N - 1;
  const __bf16* Ag0 = A  + (size_t)ar0 * K + lk;
  const __bf16* Ag1 = A  + (size_t)ar1 * K + lk;
  const __bf16* Bg0 = BT + (size_t)br0 * K + lk;
  const __bf16* Bg1 = BT + (size_t)br1 * K + lk;
  __bf16* Al = As + w * 1024;
  __bf16* Bl = Bs + w * 1024;

  f32x4 acc[4][4];
#pragma unroll
  for (int i = 0; i < 4; ++i)
#pragma unroll
    for (int j = 0; j < 4; ++j) acc[i][j] = (f32x4){0.f, 0.f, 0.f, 0.f};

  const __bf16* ap = As + (wm * 64 + (l & 15)) * 32 + (l >> 4) * 8;
  const __bf16* bp = Bs + (wn * 64 + (l & 15)) * 32 + (l >> 4) * 8;

  const int kIters = K >> 5;
  for (int kt = 0; kt < kIters; ++kt) {
    const int ko = kt * 32;
    async_copy16(Ag0 + ko, Al);
    async_copy16(Ag1 + ko, Al + 512);
    async_copy16(Bg0 + ko, Bl);
    async_copy16(Bg1 + ko, Bl + 512);
    __syncthreads();

    bf16_8 af[4], bf[4];
#pragma unroll
    for (int i = 0; i < 4; ++i) af[i] = *(const bf16_8*)(ap + i * 16 * 32);
#pragma unroll
    for (int j = 0; j < 4; ++j) bf[j] = *(const bf16_8*)(bp + j * 16 * 32);
#pragma unroll
    for (int i = 0; i < 4; ++i)
#pragma unroll
      for (int j = 0; j < 4; ++j)
        acc[i][j] = __builtin_amdgcn_mfma_f32_16x16x32_bf16(af[i], bf[j], acc[i][j], 0, 0, 0);
    __syncthreads();
  }

  const int colb = n0 + wn * 64 + (l & 15);
  const int rowb = m0 + wm * 64 + (l >> 4) * 4;

  if (OUT_BF16) {
    __bf16* Cs = (__bf16*)smem;
    const int lrb = wm * 64 + (l >> 4) * 4;
    const int lcb = wn * 64 + (l & 15);
#pragma unroll
    for (int j = 0; j < 4; ++j) {
      const float bj = bias[colb + j * 16];
#pragma unroll
      for (int i = 0; i < 4; ++i) {
#pragma unroll
        for (int r = 0; r < 4; ++r) {
          float v = acc[i][j][r] + bj;
          if (RELU) v = fmaxf(v, 0.0f);
          Cs[(lrb + i * 16 + r) * 136 + lcb + j * 16] = (__bf16)v;
        }
      }
    }
    __syncthreads();
    __bf16* Cg = (__bf16*)Cout;
#pragma unroll
    for (int it = 0; it < 8; ++it) {
      const int idx = it * 256 + tid;
      const int row = idx >> 4, c16 = idx & 15;
      const int gr = m0 + row;
      if (gr < M) {
        uint4 v = *(const uint4*)(Cs + row * 136 + c16 * 8);
        *(uint4*)(Cg + (size_t)gr * N + n0 + c16 * 8) = v;
      }
    }
  } else {
#pragma unroll
    for (int j = 0; j < 4; ++j) {
      const int gc = colb + j * 16;
      if (gc >= N) continue;
      const float bj = bias[gc];
#pragma unroll
      for (int i = 0; i < 4; ++i) {
        const int gr0 = rowb + i * 16;
#pragma unroll
        for (int r = 0; r < 4; ++r) {
          const int gr = gr0 + r;
          if (gr >= M) continue;
          float v = acc[i][j][r] + bj;
          if (RELU) v = fmaxf(v, 0.0f);
          ((float*)Cout)[(size_t)gr * N + gc] = v;
        }
      }
    }
  }
}

// ---- fused 2-layer c-MLP: Out = (relu(X@W1T^T+b1))@W2T^T+b2 ----------------
// X:(BA,256) bf16. BM=32, 256 threads, 4 waves. h in LDS, pre-tiled [kt][32][32].
__global__ __launch_bounds__(256) void mlp2_c(
    const __bf16* __restrict__ X, const __bf16* __restrict__ W1T,
    const float* __restrict__ b1, const __bf16* __restrict__ W2T,
    const float* __restrict__ b2, __bf16* __restrict__ Out)
{
  __shared__ __align__(16) __bf16 Ast[32 * 32];    //  2 KB
  __shared__ __align__(16) __bf16 Wst[256 * 32];   // 16 KB
  __shared__ __align__(16) __bf16 Hb[8 * 32 * 32]; // 16 KB
  const int tid = threadIdx.x, l = tid & 63, w = tid >> 6;
  const int m0 = blockIdx.x * 32;
  const int q4 = (l >> 4) * 4;

  f32x4 acc[2][4];
#pragma unroll
  for (int i = 0; i < 2; ++i)
#pragma unroll
    for (int j = 0; j < 4; ++j) acc[i][j] = (f32x4){0.f, 0.f, 0.f, 0.f};

  // ---- layer 1 ----
  for (int kt = 0; kt < 8; ++kt) {
    const int ko = kt * 32;
    if (tid < 128) {                       // waves 0,1 full: A tile 128 chunks
      const int ch = tid, row = ch >> 2, kk = (ch & 3) * 8;
      async_copy16(X + (size_t)(m0 + row) * Dn + ko + kk, Ast + ch * 8);
    }
#pragma unroll
    for (int r4 = 0; r4 < 4; ++r4) {       // W tile 1024 chunks
      const int ch = tid + r4 * 256, row = ch >> 2, kk = (ch & 3) * 8;
      async_copy16(W1T + (size_t)row * Dn + ko + kk, Wst + ch * 8);
    }
    __syncthreads();
    bf16_8 bf[4];
#pragma unroll
    for (int j = 0; j < 4; ++j)
      bf[j] = *(const bf16_8*)(Wst + (w * 64 + j * 16 + (l & 15)) * 32 + (l >> 4) * 8);
#pragma unroll
    for (int i = 0; i < 2; ++i) {
      bf16_8 af = *(const bf16_8*)(Ast + (i * 16 + (l & 15)) * 32 + (l >> 4) * 8);
#pragma unroll
      for (int j = 0; j < 4; ++j)
        acc[i][j] = __builtin_amdgcn_mfma_f32_16x16x32_bf16(af, bf[j], acc[i][j], 0, 0, 0);
    }
    __syncthreads();
  }

  // h = relu(acc + b1) -> pre-tiled LDS
#pragma unroll
  for (int j = 0; j < 4; ++j) {
    const int col = w * 64 + j * 16 + (l & 15);
    const float bj = b1[col];
    __bf16* hc = Hb + (col >> 5) * 1024 + (col & 31);
#pragma unroll
    for (int i = 0; i < 2; ++i)
#pragma unroll
      for (int r = 0; r < 4; ++r) {
        const int row = i * 16 + q4 + r;
        hc[row * 32] = (__bf16)fmaxf(acc[i][j][r] + bj, 0.0f);
      }
  }
  __syncthreads();

  // ---- layer 2 ----
#pragma unroll
  for (int i = 0; i < 2; ++i)
#pragma unroll
    for (int j = 0; j < 4; ++j) acc[i][j] = (f32x4){0.f, 0.f, 0.f, 0.f};
  for (int kt = 0; kt < 8; ++kt) {
    const int ko = kt * 32;
#pragma unroll
    for (int r4 = 0; r4 < 4; ++r4) {
      const int ch = tid + r4 * 256, row = ch >> 2, kk = (ch & 3) * 8;
      async_copy16(W2T + (size_t)row * Dn + ko + kk, Wst + ch * 8);
    }
    __syncthreads();
    bf16_8 bf[4];
#pragma unroll
    for (int j = 0; j < 4; ++j)
      bf[j] = *(const bf16_8*)(Wst + (w * 64 + j * 16 + (l & 15)) * 32 + (l >> 4) * 8);
#pragma unroll
    for (int i = 0; i < 2; ++i) {
      bf16_8 af = *(const bf16_8*)(Hb + kt * 1024 + (i * 16 + (l & 15)) * 32 + (l >> 4) * 8);
#pragma unroll
      for (int j = 0; j < 4; ++j)
        acc[i][j] = __builtin_amdgcn_mfma_f32_16x16x32_bf16(af, bf[j], acc[i][j], 0, 0, 0);
    }
    __syncthreads();
  }

#pragma unroll
  for (int j = 0; j < 4; ++j) {
    const int col = w * 64 + j * 16 + (l & 15);
    const float bj = b2[col];
#pragma unroll
    for (int i = 0; i < 2; ++i)
#pragma unroll
      for (int r = 0; r < 4; ++r) {
        const int row = i * 16 + q4 + r;
        Out[(size_t)(m0 + row) * Dn + col] = (__bf16)(acc[i][j][r] + bj);
      }
  }
}

// ---- fused 2-layer s-MLP + elementwise update ------------------------------
// BM=96 rows = 16 complete (ba) groups. Updates S and C masters in place.
__global__ __launch_bounds__(256) void mlp2_s(
    __bf16* __restrict__ S, const __bf16* __restrict__ W1T,
    const float* __restrict__ b1, const __bf16* __restrict__ W2T,
    const float* __restrict__ b2, const __bf16* __restrict__ Cnew,
    __bf16* __restrict__ C)
{
  // 70 KB: Ast 6K | Wst 16K | Hb 48K ; Snew (50.7K) overlays from offset 0.
  __shared__ __align__(16) char smem[71680];
  __bf16* Ast  = (__bf16*)smem;             // 96*32
  __bf16* Wst  = (__bf16*)(smem + 6144);    // 256*32
  __bf16* Hb   = (__bf16*)(smem + 22528);   // 8*96*32 pre-tiled
  __bf16* Snew = (__bf16*)smem;             // 96*264 (post-GEMM only)

  const int tid = threadIdx.x, l = tid & 63, w = tid >> 6;
  const int m0 = blockIdx.x * 96;
  const int q4 = (l >> 4) * 4;

  f32x4 acc[6][4];
#pragma unroll
  for (int i = 0; i < 6; ++i)
#pragma unroll
    for (int j = 0; j < 4; ++j) acc[i][j] = (f32x4){0.f, 0.f, 0.f, 0.f};

  // ---- layer 1 ----
  for (int kt = 0; kt < 8; ++kt) {
    const int ko = kt * 32;
    { const int ch = tid, row = ch >> 2, kk = (ch & 3) * 8;          // rows 0..63
      async_copy16(S + (size_t)(m0 + row) * Dn + ko + kk, Ast + ch * 8); }
    if (tid < 128) {                                                  // rows 64..95
      const int ch = 256 + tid, row = ch >> 2, kk = (ch & 3) * 8;
      async_copy16(S + (size_t)(m0 + row) * Dn + ko + kk, Ast + ch * 8);
    }
#pragma unroll
    for (int r4 = 0; r4 < 4; ++r4) {
      const int ch = tid + r4 * 256, row = ch >> 2, kk = (ch & 3) * 8;
      async_copy16(W1T + (size_t)row * Dn + ko + kk, Wst + ch * 8);
    }
    __syncthreads();
    bf16_8 bf[4];
#pragma unroll
    for (int j = 0; j < 4; ++j)
      bf[j] = *(const bf16_8*)(Wst + (w * 64 + j * 16 + (l & 15)) * 32 + (l >> 4) * 8);
#pragma unroll
    for (int i = 0; i < 6; ++i) {
      bf16_8 af = *(const bf16_8*)(Ast + (i * 16 + (l & 15)) * 32 + (l >> 4) * 8);
#pragma unroll
      for (int j = 0; j < 4; ++j)
        acc[i][j] = __builtin_amdgcn_mfma_f32_16x16x32_bf16(af, bf[j], acc[i][j], 0, 0, 0);
    }
    __syncthreads();
  }

  // h = relu(acc + b1) -> pre-tiled LDS [kt][96][32]
#pragma unroll
  for (int j = 0; j < 4; ++j) {
    const int col = w * 64 + j * 16 + (l & 15);
    const float bj = b1[col];
    __bf16* hc = Hb + (col >> 5) * (96 * 32) + (col & 31);
#pragma unroll
    for (int i = 0; i < 6; ++i)
#pragma unroll
      for (int r = 0; r < 4; ++r) {
        const int row = i * 16 + q4 + r;
        hc[row * 32] = (__bf16)fmaxf(acc[i][j][r] + bj, 0.0f);
      }
  }
  __syncthreads();

  // ---- layer 2 ----
#pragma unroll
  for (int i = 0; i < 6; ++i)
#pragma unroll
    for (int j = 0; j < 4; ++j) acc[i][j] = (f32x4){0.f, 0.f, 0.f, 0.f};
  for (int kt = 0; kt < 8; ++kt) {
    const int ko = kt * 32;
#pragma unroll
    for (int r4 = 0; r4 < 4; ++r4) {
      const int ch = tid + r4 * 256, row = ch >> 2, kk = (ch & 3) * 8;
      async_copy16(W2T + (size_t)row * Dn + ko + kk, Wst + ch * 8);
    }
    __syncthreads();
    bf16_8 bf[4];
#pragma unroll
    for (int j = 0; j < 4; ++j)
      bf[j] = *(const bf16_8*)(Wst + (w * 64 + j * 16 + (l & 15)) * 32 + (l >> 4) * 8);
#pragma unroll
    for (int i = 0; i < 6; ++i) {
      bf16_8 af = *(const bf16_8*)(Hb + kt * (96 * 32) + (i * 16 + (l & 15)) * 32 + (l >> 4) * 8);
#pragma unroll
      for (int j = 0; j < 4; ++j)
        acc[i][j] = __builtin_amdgcn_mfma_f32_16x16x32_bf16(af, bf[j], acc[i][j], 0, 0, 0);
    }
    __syncthreads();
  }

  // snew (raw, +b2) -> LDS (stride 264: 2-way max bank aliasing)
#pragma unroll
  for (int j = 0; j < 4; ++j) {
    const int col = w * 64 + j * 16 + (l & 15);
    const float bj = b2[col];
#pragma unroll
    for (int i = 0; i < 6; ++i)
#pragma unroll
      for (int r = 0; r < 4; ++r) {
        const int row = i * 16 + q4 + r;
        Snew[row * 264 + col] = (__bf16)(acc[i][j][r] + bj);
      }
  }
  __syncthreads();

  // fused elementwise update: 16 ba-groups x 32 d-chunks = 512 tasks
#pragma unroll
  for (int p = 0; p < 2; ++p) {
    const int q = p * 256 + tid;
    const int ba = q >> 5, dg = (q & 31) * 8;
    const size_t gb = (size_t)(blockIdx.x * 16 + ba) * Dn + dg;
    bf16_8 cn8 = *(const bf16_8*)(Cnew + gb);
    float cn[8], m[8];
#pragma unroll
    for (int e = 0; e < 8; ++e) { cn[e] = (float)cn8[e]; m[e] = -3.402823466e38f; }
#pragma unroll
    for (int t = 0; t < Tn; ++t) {
      const int row = ba * 6 + t;
      bf16_8 sn8 = *(const bf16_8*)(Snew + row * 264 + dg);
      const size_t gs = (size_t)(m0 + row) * Dn + dg;
      bf16_8 s8 = *(const bf16_8*)(S + gs);
      bf16_8 o8;
#pragma unroll
      for (int e = 0; e < 8; ++e) {
        const float sn = (float)sn8[e] * cn[e];
        m[e] = fmaxf(m[e], sn);
        o8[e] = (__bf16)(kAlpha * (float)s8[e] + kBeta * sn);
      }
      *(bf16_8*)(S + gs) = o8;
    }
    bf16_8 c8 = *(const bf16_8*)(C + gb);
#pragma unroll
    for (int e = 0; e < 8; ++e)
      c8[e] = (__bf16)(kAlpha * (float)c8[e] + kBeta * m[e]);
    *(bf16_8*)(C + gb) = c8;
  }
}

// ---- fused decoder-2 + covariance, v2: BM=128, 512 threads -----------------
__global__ __launch_bounds__(512) void decoder2_fused(
    const __bf16* __restrict__ A, const __bf16* __restrict__ BT,
    const float* __restrict__ bias, float* __restrict__ out)
{
  __shared__ __align__(16) char smem[40960];  // Ast 8K | Bst 32K ; mid 30.8K
  __bf16* Ast = (__bf16*)smem;                // 128*32
  __bf16* Bst = (__bf16*)(smem + 8192);       // 512*32
  float*  mid = (float*)smem;                 // 32*241 (post-loop)

  const int tid = threadIdx.x, l = tid & 63, w = tid >> 6;  // w 0..7
  const int m0 = blockIdx.x * 128;
  const int q4 = (l >> 4) * 4;

  f32x4 acc[8][4];
#pragma unroll
  for (int i = 0; i < 8; ++i)
#pragma unroll
    for (int j = 0; j < 4; ++j) acc[i][j] = (f32x4){0.f, 0.f, 0.f, 0.f};

  for (int kt = 0; kt < 16; ++kt) {
    const int ko = kt * 32;
    { const int ch = tid, row = ch >> 2, kk = (ch & 3) * 8;
      async_copy16(A + (size_t)(m0 + row) * Hn + ko + kk, Ast + ch * 8); }
#pragma unroll
    for (int r4 = 0; r4 < 4; ++r4) {
      const int ch = tid + r4 * 512;
      int row = ch >> 2; if (row > 400) row = 400;
      const int kk = (ch & 3) * 8;
      async_copy16(BT + (size_t)row * Hn + ko + kk, Bst + ch * 8);
    }
    __syncthreads();
    bf16_8 bf[4];
#pragma unroll
    for (int j = 0; j < 4; ++j)
      bf[j] = *(const bf16_8*)(Bst + (w * 64 + j * 16 + (l & 15)) * 32 + (l >> 4) * 8);
#pragma unroll
    for (int i = 0; i < 8; ++i) {
      bf16_8 af = *(const bf16_8*)(Ast + (i * 16 + (l & 15)) * 32 + (l >> 4) * 8);
#pragma unroll
      for (int j = 0; j < 4; ++j)
        acc[i][j] = __builtin_amdgcn_mfma_f32_16x16x32_bf16(af, bf[j], acc[i][j], 0, 0, 0);
    }
    __syncthreads();
  }

  float* cov = out + MR + (size_t)MR * 160;
  const int gc = w * 64 + (l & 15);  // + j*16
#pragma unroll
  for (int sub = 0; sub < 4; ++sub) {
    __syncthreads();
#pragma unroll
    for (int ih = 0; ih < 2; ++ih) {
      const int i = sub * 2 + ih;
#pragma unroll
      for (int j = 0; j < 4; ++j) {
        const int c = gc + j * 16;
        if (c > 400) continue;
        const float bj = bias[c];
#pragma unroll
        for (int r = 0; r < 4; ++r) {
          const int lr = ih * 16 + q4 + r;         // 0..31
          const int gr = m0 + sub * 32 + lr;
          const float v = acc[i][j][r] + bj;
          if (c < 160)      out[(size_t)MR + (size_t)gr * 160 + c] = v;
          else if (c < 400) mid[lr * 241 + (c - 160)] = v;
          else              out[gr] = v;
        }
      }
    }
    __syncthreads();
#pragma unroll
    for (int p = 0; p < 5; ++p) {
      const int q = p * 512 + tid;                 // 2560 tasks
      const int r32 = q / 80, j = q - r32 * 80;
      const int gr = m0 + sub * 32 + r32;
      const float av = mid[r32 * 241 + j];
      const float bv = mid[r32 * 241 + 80 + j];
      const float cv = mid[r32 * 241 + 160 + j];
      const float ea = expf(av), ec = expf(cv);
      const float sh = sinhf(bv), ch = coshf(bv);
      f32x4 c4 = { ea * ch * ec, sh * ec, sh * ec, ch / ea * ec };
      *(f32x4*)(cov + (size_t)gr * 320 + 4 * j) = c4;
    }
  }
}

// ---- weight transpose + bf16 convert ---------------------------------------
__global__ __launch_bounds__(256) void transpose_bf16(
    const float* __restrict__ W, __bf16* __restrict__ WT, int K, int N)
{
  __shared__ float t[32][33];
  const int b  = blockIdx.z;
  const int tx = threadIdx.x, ty = threadIdx.y;
  const int k0 = blockIdx.y * 32, n0 = blockIdx.x * 32;
  const float* Wb  = W  + (size_t)b * K * N;
  __bf16*      WTb = WT + (size_t)b * N * K;
#pragma unroll
  for (int r = 0; r < 4; ++r) {
    int kk = k0 + ty + r * 8;
    if (kk < K && n0 + tx < N) t[ty + r * 8][tx] = Wb[(size_t)kk * N + n0 + tx];
  }
  __syncthreads();
#pragma unroll
  for (int r = 0; r < 4; ++r) {
    int nn = n0 + ty + r * 8;
    if (nn < N && k0 + tx < K)
      WTb[(size_t)nn * K + k0 + tx] = (__bf16)t[tx][ty + r * 8];
  }
}

__global__ __launch_bounds__(256) void convert_bf16(
    const float* __restrict__ in, __bf16* __restrict__ out, int n)
{
  int i = blockIdx.x * 256 + threadIdx.x;
  if (i < n) out[i] = (__bf16)in[i];
}

// ---- iter-0 elementwise (init folded) --------------------------------------
__global__ __launch_bounds__(256) void ew_update0(
    const float* __restrict__ anchor, const float* __restrict__ fe,
    const float* __restrict__ snewsm, const __bf16* __restrict__ cnew,
    __bf16* __restrict__ s, __bf16* __restrict__ c)
{
  int q = blockIdx.x * 256 + threadIdx.x;
  if (q >= BA * 32) return;
  int ba = q >> 5;
  int dg = (q & 31) * 8;
  bf16_8 cn8 = *(const bf16_8*)(cnew + (size_t)ba * Dn + dg);
  float cn[8], m[8];
#pragma unroll
  for (int e = 0; e < 8; ++e) { cn[e] = (float)cn8[e]; m[e] = -3.402823466e38f; }
  size_t base = (size_t)ba * Tn * Dn + dg;
#pragma unroll
  for (int t = 0; t < Tn; ++t) {
    bf16_8 o8;
#pragma unroll
    for (int e = 0; e < 8; ++e) {
      float sn = snewsm[t * Dn + dg + e] * cn[e];
      m[e] = fmaxf(m[e], sn);
      o8[e] = (__bf16)(kAlpha * anchor[t * Dn + dg + e] + kBeta * sn);
    }
    *(bf16_8*)(s + base + t * Dn) = o8;
  }
  bf16_8 c8;
#pragma unroll
  for (int e = 0; e < 8; ++e)
    c8[e] = (__bf16)(kAlpha * fe[(size_t)ba * Dn + dg + e] + kBeta * m[e]);
  *(bf16_8*)(c + (size_t)ba * Dn + dg) = c8;
}

// ---------------------------------------------------------------------------
extern "C" void kernel_launch(void* const* d_in, const int* in_sizes, int n_in,
                              void* d_out, int out_size, void* d_ws, size_t ws_size,
                              hipStream_t stream) {
  const float* fe     = (const float*)d_in[0];
  const float* anchor = (const float*)d_in[1];
  const float* sW1 = (const float*)d_in[2];
  const float* sb1 = (const float*)d_in[3];
  const float* sW2 = (const float*)d_in[4];
  const float* sb2 = (const float*)d_in[5];
  const float* cW1 = (const float*)d_in[6];
  const float* cb1 = (const float*)d_in[7];
  const float* cW2 = (const float*)d_in[8];
  const float* cb2 = (const float*)d_in[9];
  const float* dW1 = (const float*)d_in[10];
  const float* db1 = (const float*)d_in[11];
  const float* dW2 = (const float*)d_in[12];
  const float* db2 = (const float*)d_in[13];
  float* out = (float*)d_out;

  // ---- workspace layout (bytes), total ~91.4 MB ----
  char* p = (char*)d_ws;
  __bf16* s_bf    = (__bf16*)(p + 0);            // 25,165,824
  __bf16* hd_bf   = (__bf16*)(p + 25165824);     // 50,331,648
  __bf16* c_bf    = (__bf16*)(p + 75497472);     //  4,194,304
  __bf16* cnew_bf = (__bf16*)(p + 79691776);     //  4,194,304
  __bf16* fe_bf   = (__bf16*)(p + 83886080);     //  4,194,304
  __bf16* sWT1    = (__bf16*)(p + 88080384);     //    655,360 each
  __bf16* sWT2    = (__bf16*)(p + 88735744);
  __bf16* cWT1    = (__bf16*)(p + 89391104);
  __bf16* cWT2    = (__bf16*)(p + 90046464);
  __bf16* dWT1    = (__bf16*)(p + 90701824);     //    262,144
  __bf16* dWT2    = (__bf16*)(p + 90963968);     //    410,624
  __bf16* anc_bf  = (__bf16*)(p + 91374592);     //      3,072
  __bf16* hsm_bf  = (__bf16*)(p + 91377664);     //      3,072
  float*  snewsm_f= (float* )(p + 91380736);     //      6,144

  auto gemm = [&](const __bf16* A, const __bf16* BT, const float* b, void* C,
                  int M, int N, int K, bool relu, bool outbf) {
    dim3 grid((N + 127) / 128, (M + 127) / 128);
    if (relu) {
      if (outbf) gemm_mfma<true,  true ><<<grid, 256, 0, stream>>>(A, BT, b, C, M, N, K);
      else       gemm_mfma<true,  false><<<grid, 256, 0, stream>>>(A, BT, b, C, M, N, K);
    } else {
      if (outbf) gemm_mfma<false, true ><<<grid, 256, 0, stream>>>(A, BT, b, C, M, N, K);
      else       gemm_mfma<false, false><<<grid, 256, 0, stream>>>(A, BT, b, C, M, N, K);
    }
  };

  // ---- weight prep ----
  {
    dim3 blk(32, 8);
    dim3 g88(8, 8, NBn);
    transpose_bf16<<<g88, blk, 0, stream>>>(sW1, sWT1, Dn, Dn);
    transpose_bf16<<<g88, blk, 0, stream>>>(sW2, sWT2, Dn, Dn);
    transpose_bf16<<<g88, blk, 0, stream>>>(cW1, cWT1, Dn, Dn);
    transpose_bf16<<<g88, blk, 0, stream>>>(cW2, cWT2, Dn, Dn);
    transpose_bf16<<<dim3(16, 8, 1), blk, 0, stream>>>(dW1, dWT1, Dn, Hn);
    transpose_bf16<<<dim3(13, 16, 1), blk, 0, stream>>>(dW2, dWT2, Hn, OUTn);
  }
  convert_bf16<<<(BA * Dn + 255) / 256, 256, 0, stream>>>(fe, fe_bf, BA * Dn);
  convert_bf16<<<(Tn * Dn + 255) / 256, 256, 0, stream>>>(anchor, anc_bf, Tn * Dn);

  const size_t WKK = (size_t)Dn * Dn;

  // ---- iteration 0 (s-branch on 6 anchor rows; c-branch fused MLP) ----
  gemm(anc_bf, sWT1, sb1, hsm_bf,   Tn, Dn, Dn, true,  true);
  gemm(hsm_bf, sWT2, sb2, snewsm_f, Tn, Dn, Dn, false, false);
  mlp2_c<<<BA / 32, 256, 0, stream>>>(fe_bf, cWT1, cb1, cWT2, cb2, cnew_bf);
  ew_update0<<<(BA * 32 + 255) / 256, 256, 0, stream>>>(anchor, fe, snewsm_f,
                                                        cnew_bf, s_bf, c_bf);

  // ---- iterations 1..4: two fused kernels each ----
  for (int i = 1; i < NBn; ++i) {
    mlp2_c<<<BA / 32, 256, 0, stream>>>(c_bf, cWT1 + i * WKK, cb1 + i * Dn,
                                        cWT2 + i * WKK, cb2 + i * Dn, cnew_bf);
    mlp2_s<<<MR / 96, 256, 0, stream>>>(s_bf, sWT1 + i * WKK, sb1 + i * Dn,
                                        sWT2 + i * WKK, sb2 + i * Dn,
                                        cnew_bf, c_bf);
  }

  // ---- decoder ----
  gemm(s_bf, dWT1, db1, hd_bf, MR, Hn, Dn, true, true);
  decoder2_fused<<<MR / 128, 512, 0, stream>>>(hd_bf, dWT2, db2, out);
}